// Round 2
// 347.894 us; speedup vs baseline: 1.0972x; 1.0972x over previous
//
#include <hip/hip_runtime.h>
#include <stdint.h>

typedef _Float16 f16;
typedef __attribute__((ext_vector_type(8))) _Float16 f16x8;
typedef __attribute__((ext_vector_type(4))) float f32x4;

#define NN 4096
#define UN 256

__device__ __forceinline__ f16x8 ld_f16x8(const f16* p){ return *(const f16x8*)p; }
__device__ __forceinline__ f32x4 zero4(){ f32x4 z = {0.f,0.f,0.f,0.f}; return z; }

// Fragment-major B layout: [k/32][n/16][lane=((k>>3)&3)*16+(n&15)][j=k&7] f16.
// A wave loads fragment (kc,nt) as one coalesced 1KB read: base + lane*8.

// ---------------- K0: build wgB (f16 frag-major) + gate frag buffers ------
__global__ __launch_bounds__(256) void k0_prep(
    const float* __restrict__ wg, const float* __restrict__ wz,
    const float* __restrict__ uz, const float* __restrict__ wh,
    const float* __restrict__ uh,
    f16* __restrict__ wgB,
    f16* __restrict__ czB_h, f16* __restrict__ czB_l,
    f16* __restrict__ chB_h, f16* __restrict__ chB_l)
{
  __shared__ float lsA[32*256];
  __shared__ float lsB[32*256];
  const int t = threadIdx.x;
  const int b = blockIdx.x;
  if (b < 128){
    const int kcg = b;
    #pragma unroll 8
    for (int i = 0; i < 32; i++)
      lsA[i*256 + t] = wg[(size_t)(kcg*32 + i) * UN + t];
    __syncthreads();
    #pragma unroll
    for (int i = 0; i < 4; i++){
      int o = i*256 + t;
      int l = o & 63;
      int n = ((o >> 6) << 4) + (l & 15);
      int kl = (l >> 4) * 8;
      f16 v8[8];
      #pragma unroll
      for (int j = 0; j < 8; j++) v8[j] = (f16)lsA[(kl + j)*256 + n];
      *(uint4*)(wgB + ((size_t)kcg*1024 + o)*8) = *(const uint4*)v8;
    }
  } else {
    const int kcg = b - 128;           // 0..15, K=512
    #pragma unroll 8
    for (int i = 0; i < 32; i++){
      int kg = kcg*32 + i;
      lsA[i*256 + t] = (kg < 256) ? wz[(size_t)kg * UN + t]
                                  : uz[(size_t)(kg - 256) * UN + t];
      lsB[i*256 + t] = (kg < 256) ? wh[(size_t)kg * UN + t]
                                  : uh[(size_t)(kg - 256) * UN + t];
    }
    __syncthreads();
    #pragma unroll
    for (int i = 0; i < 4; i++){
      int o = i*256 + t;
      int l = o & 63;
      int n = ((o >> 6) << 4) + (l & 15);
      int kl = (l >> 4) * 8;
      f16 zh[8], zl[8], hh[8], hl[8];
      #pragma unroll
      for (int j = 0; j < 8; j++){
        float vz = lsA[(kl + j)*256 + n];
        float vh = lsB[(kl + j)*256 + n];
        f16 a = (f16)vz; zh[j] = a; zl[j] = (f16)(vz - (float)a);
        f16 c = (f16)vh; hh[j] = c; hl[j] = (f16)(vh - (float)c);
      }
      size_t off = ((size_t)kcg*1024 + o)*8;
      *(uint4*)(czB_h + off) = *(const uint4*)zh;
      *(uint4*)(czB_l + off) = *(const uint4*)zl;
      *(uint4*)(chB_h + off) = *(const uint4*)hh;
      *(uint4*)(chB_l + off) = *(const uint4*)hl;
    }
  }
}

// ---------------- K1: W2p[split] = (sum_g wa_g adj_g) @ w_gcn (K-slice) ---
// No LDS/barriers/atomics. Block = 4 waves x 16 rows; grid (64 m, 8 k-splits
// of 512). Each block stores its partial tile to a private slab.
__global__ __launch_bounds__(256) void k1_w2(
    const float* __restrict__ adj, const float* __restrict__ wa,
    const f16* __restrict__ wgB, float* __restrict__ W2p)
{
  const int t = threadIdx.x, lane = t & 63, wv = t >> 6;
  const int qm = lane & 15, quad = lane >> 4;
  const int mbase = blockIdx.x * 64 + wv * 16;
  const int kbase = blockIdx.y * 512;
  const float wa0 = wa[0], wa1 = wa[1], wa2 = wa[2];
  const size_t gs = (size_t)NN * NN;
  const float* pa = adj + (size_t)(mbase + qm) * NN + kbase + quad * 8;

  f32x4 acc[16];
  #pragma unroll
  for (int i = 0; i < 16; i++) acc[i] = zero4();

  // A prefetch registers (current step)
  f32x4 g[6];
  #pragma unroll
  for (int r = 0; r < 2; r++)
    #pragma unroll
    for (int gi = 0; gi < 3; gi++)
      g[gi*2 + r] = *(const f32x4*)(pa + (size_t)gi*gs + r*4);

  for (int step = 0; step < 16; step++){
    const int kc = step * 32;
    const int kcg = (kbase + kc) >> 5;
    const f16* pb = wgB + ((size_t)kcg*1024 + lane)*8;

    // first half of B fragments
    f16x8 bf[8];
    #pragma unroll
    for (int i = 0; i < 8; i++) bf[i] = ld_f16x8(pb + i*512);

    // mix current A (VALU; overlaps in-flight B loads)
    f16x8 ah, al;
    #pragma unroll
    for (int j = 0; j < 4; j++){
      float v0 = wa0*g[0][j] + wa1*g[2][j] + wa2*g[4][j];
      float v1 = wa0*g[1][j] + wa1*g[3][j] + wa2*g[5][j];
      f16 h0 = (f16)v0, h1 = (f16)v1;
      ah[j] = h0;   al[j] = (f16)(v0 - (float)h0);
      ah[4+j] = h1; al[4+j] = (f16)(v1 - (float)h1);
    }

    // prefetch next step's A
    f32x4 gn[6];
    if (step < 15){
      const float* pan = pa + kc + 32;
      #pragma unroll
      for (int r = 0; r < 2; r++)
        #pragma unroll
        for (int gi = 0; gi < 3; gi++)
          gn[gi*2 + r] = *(const f32x4*)(pan + (size_t)gi*gs + r*4);
    }

    // second half of B fragments
    f16x8 bg[8];
    #pragma unroll
    for (int i = 0; i < 8; i++) bg[i] = ld_f16x8(pb + (8+i)*512);

    #pragma unroll
    for (int tn = 0; tn < 8; tn++){
      acc[tn] = __builtin_amdgcn_mfma_f32_16x16x32_f16(ah, bf[tn], acc[tn], 0, 0, 0);
      acc[tn] = __builtin_amdgcn_mfma_f32_16x16x32_f16(al, bf[tn], acc[tn], 0, 0, 0);
    }
    #pragma unroll
    for (int tn = 0; tn < 8; tn++){
      acc[8+tn] = __builtin_amdgcn_mfma_f32_16x16x32_f16(ah, bg[tn], acc[8+tn], 0, 0, 0);
      acc[8+tn] = __builtin_amdgcn_mfma_f32_16x16x32_f16(al, bg[tn], acc[8+tn], 0, 0, 0);
    }

    #pragma unroll
    for (int i = 0; i < 6; i++) g[i] = gn[i];
  }

  // epilogue: plain stores to this split's private slab (no atomics)
  float* wout = W2p + (size_t)blockIdx.y * ((size_t)NN * UN);
  #pragma unroll
  for (int tn = 0; tn < 16; tn++)
    #pragma unroll
    for (int r = 0; r < 4; r++)
      wout[(size_t)(mbase + quad*4 + r)*UN + tn*16 + qm] = acc[tn][r];
}

// ---------------- Kcvt: sum 8 W2 partials -> W2B f16 frag-major -----------
__global__ __launch_bounds__(256) void k_cvt(
    const float* __restrict__ W2p, f16* __restrict__ W2B)
{
  __shared__ float ls[32*256];
  const int t = threadIdx.x;
  const int kcg = blockIdx.x;            // 0..127
  const int r0 = t >> 6;                 // 0..3
  const int c0 = (t & 63) * 4;
  #pragma unroll
  for (int i = 0; i < 8; i++){
    int r = i*4 + r0;
    const float* src = W2p + (size_t)(kcg*32 + r) * UN + c0;
    f32x4 s = zero4();
    #pragma unroll
    for (int p = 0; p < 8; p++)
      s = s + *(const f32x4*)(src + (size_t)p * ((size_t)NN*UN));
    *(f32x4*)(ls + r*256 + c0) = s;
  }
  __syncthreads();
  #pragma unroll
  for (int i = 0; i < 4; i++){
    int o = i*256 + t;
    int l = o & 63;
    int n = ((o >> 6) << 4) + (l & 15);
    int kl = (l >> 4) * 8;
    f16 v8[8];
    #pragma unroll
    for (int j = 0; j < 8; j++) v8[j] = (f16)ls[(kl + j)*256 + n];
    *(uint4*)(W2B + ((size_t)kcg*1024 + o)*8) = *(const uint4*)v8;
  }
}

// ---------------- K2: xgp[split] = inputs @ W2 (K-slice) ------------------
__global__ __launch_bounds__(256) void k2_x(
    const float* __restrict__ inputs, const f16* __restrict__ W2B,
    float* __restrict__ xgp)
{
  const int t = threadIdx.x, lane = t & 63, wv = t >> 6;
  const int qm = lane & 15, quad = lane >> 4;
  const int m0 = blockIdx.x * 16;
  const int kbase = blockIdx.y * 512;
  const float* pa = inputs + (size_t)(m0 + qm) * NN + kbase + quad * 8;

  f32x4 acc[4] = { zero4(), zero4(), zero4(), zero4() };

  #pragma unroll 4
  for (int kc = 0; kc < 512; kc += 32){
    f32x4 a0 = *(const f32x4*)(pa + kc);
    f32x4 a1 = *(const f32x4*)(pa + kc + 4);
    const int kcg = (kbase + kc) >> 5;
    const f16* pb = W2B + (((size_t)kcg*16 + wv*4)*64 + lane)*8;
    f16x8 bfr[4];
    #pragma unroll
    for (int tn = 0; tn < 4; tn++) bfr[tn] = ld_f16x8(pb + tn*512);
    f16x8 ah, al;
    #pragma unroll
    for (int j = 0; j < 4; j++){
      f16 h0 = (f16)a0[j], h1 = (f16)a1[j];
      ah[j] = h0;   al[j] = (f16)(a0[j] - (float)h0);
      ah[4+j] = h1; al[4+j] = (f16)(a1[j] - (float)h1);
    }
    #pragma unroll
    for (int tn = 0; tn < 4; tn++){
      acc[tn] = __builtin_amdgcn_mfma_f32_16x16x32_f16(ah, bfr[tn], acc[tn], 0, 0, 0);
      acc[tn] = __builtin_amdgcn_mfma_f32_16x16x32_f16(al, bfr[tn], acc[tn], 0, 0, 0);
    }
  }
  float* xo = xgp + (size_t)blockIdx.y * ((size_t)512 * UN);
  #pragma unroll
  for (int tn = 0; tn < 4; tn++)
    #pragma unroll
    for (int r = 0; r < 4; r++)
      xo[(size_t)(m0 + quad*4 + r)*UN + (wv*4 + tn)*16 + qm] = acc[tn][r];
}

// ---------------- K2b: xa = f16 hi/lo of [relu(sum xgp) | state] ----------
__global__ __launch_bounds__(256) void k2b_xa(
    const float* __restrict__ xgp, const float* __restrict__ state,
    f16* __restrict__ xa_h, f16* __restrict__ xa_l)
{
  const size_t e = ((size_t)blockIdx.x * 256 + threadIdx.x) * 8;
  const int m = (int)(e >> 9), k0 = (int)(e & 511);
  const bool rl = (k0 < 256);
  f32x4 a, b;
  if (rl){
    const float* src = xgp + (size_t)m * UN + k0;
    a = zero4(); b = zero4();
    #pragma unroll
    for (int p = 0; p < 8; p++){
      a = a + *(const f32x4*)(src + (size_t)p * (512*UN));
      b = b + *(const f32x4*)(src + (size_t)p * (512*UN) + 4);
    }
  } else {
    const float* src = state + (size_t)m * UN + (k0 - 256);
    a = *(const f32x4*)src;
    b = *(const f32x4*)(src + 4);
  }
  f16 hi[8], lo[8];
  #pragma unroll
  for (int j = 0; j < 4; j++){
    float va = rl ? fmaxf(a[j], 0.f) : a[j];
    float vb = rl ? fmaxf(b[j], 0.f) : b[j];
    f16 ha = (f16)va, hb = (f16)vb;
    hi[j] = ha;   lo[j] = (f16)(va - (float)ha);
    hi[4+j] = hb; lo[4+j] = (f16)(vb - (float)hb);
  }
  *(uint4*)(xa_h + e) = *(const uint4*)hi;
  *(uint4*)(xa_l + e) = *(const uint4*)lo;
}

// ---------------- K3: gate logits via MFMA, 8-way K-split, no atomics -----
// Grid (32 m-tiles of 16, 8 k-splits of 64). Waves = n-quarters. Both gates.
__global__ __launch_bounds__(256) void k3_gates(
    const f16* __restrict__ xa_h, const f16* __restrict__ xa_l,
    const f16* __restrict__ czB_h, const f16* __restrict__ czB_l,
    const f16* __restrict__ chB_h, const f16* __restrict__ chB_l,
    float* __restrict__ lzp, float* __restrict__ lhp)
{
  const int t = threadIdx.x, lane = t & 63, wv = t >> 6;
  const int qm = lane & 15, quad = lane >> 4;
  const int m0 = blockIdx.x * 16;
  const int kbase = blockIdx.y * 64;

  f32x4 az[4] = { zero4(), zero4(), zero4(), zero4() };
  f32x4 ag[4] = { zero4(), zero4(), zero4(), zero4() };

  #pragma unroll
  for (int kk = 0; kk < 2; kk++){
    const int kb = kbase + kk*32;
    const size_t pao = (size_t)(m0 + qm) * 512 + kb + quad * 8;
    f16x8 ah = ld_f16x8(xa_h + pao);
    f16x8 al = ld_f16x8(xa_l + pao);
    const int kcg = kb >> 5;
    const size_t base = (((size_t)kcg*16 + wv*4)*64 + lane)*8;
    #pragma unroll
    for (int tn = 0; tn < 4; tn++){
      f16x8 bzh = ld_f16x8(czB_h + base + tn*512);
      f16x8 bzl = ld_f16x8(czB_l + base + tn*512);
      f16x8 bhh = ld_f16x8(chB_h + base + tn*512);
      f16x8 bhl = ld_f16x8(chB_l + base + tn*512);
      az[tn] = __builtin_amdgcn_mfma_f32_16x16x32_f16(ah, bzh, az[tn], 0, 0, 0);
      az[tn] = __builtin_amdgcn_mfma_f32_16x16x32_f16(al, bzh, az[tn], 0, 0, 0);
      az[tn] = __builtin_amdgcn_mfma_f32_16x16x32_f16(ah, bzl, az[tn], 0, 0, 0);
      ag[tn] = __builtin_amdgcn_mfma_f32_16x16x32_f16(ah, bhh, ag[tn], 0, 0, 0);
      ag[tn] = __builtin_amdgcn_mfma_f32_16x16x32_f16(al, bhh, ag[tn], 0, 0, 0);
      ag[tn] = __builtin_amdgcn_mfma_f32_16x16x32_f16(ah, bhl, ag[tn], 0, 0, 0);
    }
  }
  float* oz = lzp + (size_t)blockIdx.y * ((size_t)512 * UN);
  float* oh = lhp + (size_t)blockIdx.y * ((size_t)512 * UN);
  #pragma unroll
  for (int tn = 0; tn < 4; tn++)
    #pragma unroll
    for (int r = 0; r < 4; r++){
      size_t o = (size_t)(m0 + quad*4 + r)*UN + (wv*4 + tn)*16 + qm;
      oz[o] = az[tn][r];
      oh[o] = ag[tn][r];
    }
}

// ---------------- K3b: sum partials + elementwise gates + output ----------
__global__ __launch_bounds__(256) void k3b_out(
    const float* __restrict__ lzp, const float* __restrict__ lhp,
    const float* __restrict__ state,
    const float* __restrict__ bz, const float* __restrict__ bh,
    float* __restrict__ out)
{
  const size_t e = ((size_t)blockIdx.x * 256 + threadIdx.x) * 4;
  const int n = (int)(e & 255);
  f32x4 z4 = zero4(), h4 = zero4();
  #pragma unroll
  for (int p = 0; p < 8; p++){
    z4 = z4 + *(const f32x4*)(lzp + (size_t)p * (512*UN) + e);
    h4 = h4 + *(const f32x4*)(lhp + (size_t)p * (512*UN) + e);
  }
  f32x4 s4 = *(const f32x4*)(state + e);
  f32x4 bz4 = *(const f32x4*)(bz + n);
  f32x4 bh4 = *(const f32x4*)(bh + n);
  f32x4 o4;
  #pragma unroll
  for (int j = 0; j < 4; j++){
    float z = 1.f / (1.f + __expf(-(z4[j] + bz4[j])));
    float ex = __expf(2.f * (h4[j] + bh4[j]));
    float hh = 1.f - 2.f / (ex + 1.f);
    o4[j] = (1.f - z) * s4[j] + z * hh;
  }
  *(f32x4*)(out + e) = o4;
}

// ---------------- launch --------------------------------------------------
extern "C" void kernel_launch(void* const* d_in, const int* in_sizes, int n_in,
                              void* d_out, int out_size, void* d_ws, size_t ws_size,
                              hipStream_t stream)
{
  const float* inputs = (const float*)d_in[0];
  const float* state  = (const float*)d_in[1];
  const float* adj    = (const float*)d_in[2];
  const float* wa     = (const float*)d_in[3];
  const float* wg     = (const float*)d_in[4];
  const float* wz     = (const float*)d_in[5];
  const float* uz     = (const float*)d_in[6];
  const float* bz     = (const float*)d_in[7];
  const float* wh     = (const float*)d_in[8];
  const float* uh     = (const float*)d_in[9];
  const float* bh     = (const float*)d_in[10];
  float* out = (float*)d_out;

  char* ws = (char*)d_ws;
  float* W2p   = (float*)(ws);                          // 32 MB: 8 x [4096][256] f32
  float* xgp   = (float*)(ws + (32u<<20));              // 4 MB: 8 x [512][256] f32
  float* lzp   = (float*)(ws + (36u<<20));              // 4 MB
  float* lhp   = (float*)(ws + (40u<<20));              // 4 MB
  f16* wgB     = (f16*)(ws + (44u<<20));                // 2 MB frag-major
  f16* W2B     = (f16*)(ws + (46u<<20));                // 2 MB frag-major
  f16* xa_h    = (f16*)(ws + (48u<<20));                // 512 KB [512][512]
  f16* xa_l    = (f16*)(ws + (48u<<20) + (512u<<10));   // 512 KB
  f16* czB_h   = (f16*)(ws + (49u<<20));                // 256 KB
  f16* czB_l   = (f16*)(ws + (49u<<20) + (256u<<10));   // 256 KB
  f16* chB_h   = (f16*)(ws + (49u<<20) + (512u<<10));   // 256 KB
  f16* chB_l   = (f16*)(ws + (49u<<20) + (768u<<10));   // 256 KB

  // no memset needed: every partial slab is fully overwritten before read
  k0_prep<<<144, 256, 0, stream>>>(wg, wz, uz, wh, uh,
                                   wgB, czB_h, czB_l, chB_h, chB_l);
  k1_w2<<<dim3(64, 8), 256, 0, stream>>>(adj, wa, wgB, W2p);
  k_cvt<<<128, 256, 0, stream>>>(W2p, W2B);
  k2_x<<<dim3(32, 8), 256, 0, stream>>>(inputs, W2B, xgp);
  k2b_xa<<<128, 256, 0, stream>>>(xgp, state, xa_h, xa_l);
  k3_gates<<<dim3(32, 8), 256, 0, stream>>>(xa_h, xa_l, czB_h, czB_l,
                                            chB_h, chB_l, lzp, lhp);
  k3b_out<<<128, 256, 0, stream>>>(lzp, lhp, state, bz, bh, out);
}